// Round 4
// baseline (430.910 us; speedup 1.0000x reference)
//
#include <hip/hip_runtime.h>

typedef __attribute__((ext_vector_type(8))) _Float16 half8;
typedef __attribute__((ext_vector_type(4))) float floatx4;

#define AS1 __attribute__((address_space(1)))
#define AS3 __attribute__((address_space(3)))

__device__ __forceinline__ void async_load16(const void* g, void* l) {
  __builtin_amdgcn_global_load_lds((AS1 void*)(unsigned long long)g,
                                   (AS3 void*)(unsigned long long)l, 16, 0, 0);
}

// ---------------- GroupNorm stats: one block per (b, g); region is contiguous 16*2048 floats
__global__ __launch_bounds__(256) void gn_stats(const float* __restrict__ x,
                                                float* __restrict__ stats) {
  const int bg = blockIdx.x;
  const float4* p4 = (const float4*)(x + (long long)bg * 32768);
  const int t = threadIdx.x;
  float s = 0.f, ss = 0.f;
  for (int i = t; i < 8192; i += 256) {
    float4 v = p4[i];
    s += v.x + v.y + v.z + v.w;
    ss += v.x * v.x + v.y * v.y + v.z * v.z + v.w * v.w;
  }
#pragma unroll
  for (int off = 32; off; off >>= 1) { s += __shfl_down(s, off); ss += __shfl_down(ss, off); }
  __shared__ float rs[4], rss[4];
  if ((t & 63) == 0) { rs[t >> 6] = s; rss[t >> 6] = ss; }
  __syncthreads();
  if (t == 0) {
    s = rs[0] + rs[1] + rs[2] + rs[3];
    ss = rss[0] + rss[1] + rss[2] + rss[3];
    float mean = s * (1.f / 32768.f);
    float var = ss * (1.f / 32768.f) - mean * mean;
    stats[bg] = mean;
    stats[256 + bg] = rsqrtf(var + 1e-5f);
  }
}

// ---------------- normalize + transpose: x[b,c,l] fp32 -> ht[b,l,c] fp16
__global__ __launch_bounds__(256) void gn_apply(const float* __restrict__ x,
                                                const float* __restrict__ stats,
                                                const float* __restrict__ gsc,
                                                const float* __restrict__ gbi,
                                                _Float16* __restrict__ ht) {
  __shared__ float tile[64][65];
  const int b = blockIdx.z, c0 = blockIdx.y * 64, l0 = blockIdx.x * 64;
  const int t = threadIdx.x, tr = t >> 6, tc = t & 63;
  const float* xb = x + ((long long)b * 512 + c0) * 2048 + l0;
#pragma unroll
  for (int p = 0; p < 16; ++p) {
    int row = tr + p * 4;
    tile[row][tc] = xb[(long long)row * 2048 + tc];
  }
  __syncthreads();
  const int c = c0 + tc;
  const int bg = b * 32 + (c >> 4);
  const float mean = stats[bg], rstd = stats[256 + bg];
  const float sc = gsc[c] * rstd;
  const float off = gbi[c] - mean * sc;
  _Float16* hb = ht + ((long long)b * 2048 + l0) * 512 + c0;
#pragma unroll
  for (int p = 0; p < 16; ++p) {
    int l = tr + p * 4;
    hb[(long long)l * 512 + tc] = (_Float16)(tile[tc][l] * sc + off);
  }
}

// ---------------- cast 4 weight matrices fp32 -> fp16, plus pack bq||bk into bqk (f32)
__global__ __launch_bounds__(256) void cast_w(const float* __restrict__ w0, const float* __restrict__ w1,
                                              const float* __restrict__ w2, const float* __restrict__ w3,
                                              const float* __restrict__ bq, const float* __restrict__ bk,
                                              _Float16* __restrict__ outw, float* __restrict__ bqk) {
  const long long i = (long long)blockIdx.x * 256 + threadIdx.x;
  if (blockIdx.x < 4096) {
    const int m = (int)(i >> 18);
    const int r = (int)(i & 262143);
    const float* w = (m == 0) ? w0 : (m == 1) ? w1 : (m == 2) ? w2 : w3;
    outw[i] = (_Float16)w[r];
  } else {
    const int j = (int)(i - 4096LL * 256);  // 0..1023
    bqk[j] = (j < 512) ? bq[j] : bk[j - 512];
  }
}

// ---------------- generic C[M,N] = alpha * A[M,K] * Bt[N,K]^T (+bias)(+residual)
// 128x128 tile, BK=64, XOR-swizzled LDS (conflict-free ds_read_b128),
// 4 waves x (4x4) mfma_f32_16x16x32_f16, global_load_lds width-16 staging.
// Grid: x = batch (XCD-local), y = m-tile, z = n-tile.
template <int BIAS_MODE /*0 none,1 over n,2 over m*/, int OUT_TYPE /*0 f32,1 f16*/, bool RESIDUAL>
__global__ __launch_bounds__(256) void gemm_bt(
    const _Float16* __restrict__ A, long long sA, int lda,
    const _Float16* __restrict__ Bt, long long sB, int ldb,
    void* __restrict__ Cv, long long sC, int ldc,
    const float* __restrict__ bias,
    const float* __restrict__ resid, long long sR,
    float alpha, int K) {
  __shared__ __align__(16) _Float16 lsa[128 * 64];
  __shared__ __align__(16) _Float16 lsb[128 * 64];
  const int tid = threadIdx.x;
  const int wave = tid >> 6, lane = tid & 63;
  const int bz = blockIdx.x;  // batch -> XCD (linear_id % 8 == batch)
  const int m0 = blockIdx.y * 128, n0 = blockIdx.z * 128;
  A += (long long)bz * sA;
  Bt += (long long)bz * sB;

  const bool isA = (wave < 2);
  const _Float16* gsrc = isA ? A : Bt;
  const int ld = isA ? lda : ldb;
  const int rbase = (wave & 1) * 64;
  const int t0 = isA ? m0 : n0;
  _Float16* lbase = (isA ? lsa : lsb) + rbase * 64;
  const int grow = t0 + rbase + (lane >> 3);
  const int gcol = ((lane & 7) ^ ((lane >> 3) & 7)) * 8;

  floatx4 acc[4][4] = {};
  const int mw = (wave >> 1) * 64, nw = (wave & 1) * 64;
  const int fm = lane & 15;
  const int quad = lane >> 4;

  for (int k0 = 0; k0 < K; k0 += 64) {
    __syncthreads();
    const _Float16* g = gsrc + (long long)grow * ld + k0 + gcol;
#pragma unroll
    for (int s = 0; s < 8; ++s)
      async_load16(g + (long long)s * 8 * ld, lbase + s * 512);
    __syncthreads();
#pragma unroll
    for (int kk = 0; kk < 2; ++kk) {
      const int ca = quad + 4 * kk;
      const int cs = (ca ^ (fm & 7)) * 8;
      half8 af[4], bfr[4];
#pragma unroll
      for (int i = 0; i < 4; ++i) af[i] = *(const half8*)&lsa[(mw + 16 * i + fm) * 64 + cs];
#pragma unroll
      for (int j = 0; j < 4; ++j) bfr[j] = *(const half8*)&lsb[(nw + 16 * j + fm) * 64 + cs];
#pragma unroll
      for (int i = 0; i < 4; ++i)
#pragma unroll
        for (int j = 0; j < 4; ++j)
          acc[i][j] = __builtin_amdgcn_mfma_f32_16x16x32_f16(af[i], bfr[j], acc[i][j], 0, 0, 0);
    }
  }

  const int r0 = m0 + mw + quad * 4;
  const int c0 = n0 + nw + fm;
#pragma unroll
  for (int i = 0; i < 4; ++i) {
#pragma unroll
    for (int j = 0; j < 4; ++j) {
      const int cc = c0 + 16 * j;
#pragma unroll
      for (int t = 0; t < 4; ++t) {
        const int rr = r0 + 16 * i + t;
        float v = acc[i][j][t] * alpha;
        if (BIAS_MODE == 1) v += bias[cc];
        if (BIAS_MODE == 2) v += bias[rr];
        if (RESIDUAL) v += resid[(long long)bz * sR + (long long)rr * ldc + cc];
        const long long off = (long long)bz * sC + (long long)rr * ldc + cc;
        if (OUT_TYPE == 0) ((float*)Cv)[off] = v;
        else ((_Float16*)Cv)[off] = (_Float16)v;
      }
    }
  }
}

// ---------------- flash attention v2: S=qk^T -> online softmax -> PV.
// Block = 128 threads (2 waves x 16 q-rows = 32 q), grid (batch=8, qtile=64)
// -> 512 blocks, 2 blocks/CU (66 KB LDS). Single-buffered k/v; co-resident
// block covers the staging barrier. vbuf uses 128-B super-rows (2 c-rows)
// with xor chunk swizzle -> full 32-bank coverage, 2-way (free) PV reads.
// Row-sum rides an extra MFMA with an all-ones B fragment.
__global__ __launch_bounds__(128) void flash_attn(
    const _Float16* __restrict__ qk,  // [b, l, 1024] (q | k)
    const _Float16* __restrict__ vm,  // [b, c, l]  (V^T)
    _Float16* __restrict__ at) {      // [b, l, c]
  __shared__ __align__(16) _Float16 kbuf[32 * 512];   // 32 KB: [l-row][c], chunk^row swizzle
  __shared__ __align__(16) _Float16 vbuf[256 * 64];   // 32 KB: super-row = 2 c-rows
  __shared__ __align__(16) _Float16 Pls[2][16 * 34];  // 2176 B, stride 34 (odd dwords)
  const int tid = threadIdx.x, wave = tid >> 6, lane = tid & 63;
  const int fm = lane & 15, quad = lane >> 4;
  const int b = blockIdx.x, q0 = blockIdx.y * 32;
  const _Float16* qb = qk + (long long)b * 2097152;
  const _Float16* kb = qb + 512;
  const _Float16* vb = vm + (long long)b * 1048576;

  // q A-frags: rows q0+16*wave+fm, k-chunk ks*32+quad*8, pre-scaled by 512^-0.5
  half8 qf[16];
  {
    const _Float16* qrow = qb + (long long)(q0 + 16 * wave + fm) * 1024 + quad * 8;
#pragma unroll
    for (int ks = 0; ks < 16; ++ks) {
      half8 h = *(const half8*)(qrow + ks * 32);
#pragma unroll
      for (int e = 0; e < 8; ++e) h[e] = (_Float16)((float)h[e] * 0.044194173824159216f);
      qf[ks] = h;
    }
  }

  half8 ones;
#pragma unroll
  for (int e = 0; e < 8; ++e) ones[e] = (_Float16)1.0f;

  floatx4 o[32] = {};   // O rows 16w+quad*4+t, cols fm+16j
  floatx4 lacc = {};    // row-sum accumulator (same C-layout rows)
  float m_i[4];
#pragma unroll
  for (int t = 0; t < 4; ++t) m_i[t] = -1e30f;

  auto stage = [&](int l0) {
    // k-tile [32 l-rows x 512 c]: chunk ch of row stored at ch^(row&7)
#pragma unroll
    for (int s = 0; s < 16; ++s) {
      int i = s * 128 + tid;
      int row = i >> 6, ch = i & 63;
      async_load16(kb + (long long)(l0 + row) * 1024 + ((ch ^ (row & 7)) << 3),
                   kbuf + i * 8);
    }
    // v-tile: super-row r holds c=2r (l 0..31) then c=2r+1; chunk swizzle ^(r&7)
#pragma unroll
    for (int s = 0; s < 16; ++s) {
      int i = s * 128 + tid;
      int r = i >> 3, ch = (i & 7) ^ (r & 7);
      async_load16(vb + (long long)(2 * r + (ch >> 2)) * 2048 + l0 + ((ch & 3) << 3),
                   vbuf + i * 8);
    }
  };

  stage(0);
  for (int kt = 0; kt < 64; ++kt) {
    __syncthreads();  // staging drained (vmcnt0 before barrier)

    // S-tile: rows 16w+quad*4+t, cols kt*32 + fm+16j
    floatx4 sacc[2] = {};
#pragma unroll
    for (int ks = 0; ks < 16; ++ks) {
#pragma unroll
      for (int j = 0; j < 2; ++j) {
        const int ch = (ks * 4 + quad) ^ (fm & 7);
        half8 bf = *(const half8*)&kbuf[(16 * j + fm) * 512 + ch * 8];
        sacc[j] = __builtin_amdgcn_mfma_f32_16x16x32_f16(qf[ks], bf, sacc[j], 0, 0, 0);
      }
    }

    // online softmax: max over row (16 lanes of this quad), exp in place
    float alpha[4];
#pragma unroll
    for (int t = 0; t < 4; ++t) {
      float mx = fmaxf(sacc[0][t], sacc[1][t]);
#pragma unroll
      for (int d = 1; d < 16; d <<= 1) mx = fmaxf(mx, __shfl_xor(mx, d));
      float mn = fmaxf(m_i[t], mx);
      alpha[t] = __expf(m_i[t] - mn);
      m_i[t] = mn;
      sacc[0][t] = __expf(sacc[0][t] - mn);
      sacc[1][t] = __expf(sacc[1][t] - mn);
    }

    // P: C-layout -> wave-private LDS -> A-layout (lgkmcnt ordering only)
#pragma unroll
    for (int j = 0; j < 2; ++j)
#pragma unroll
      for (int t = 0; t < 4; ++t)
        Pls[wave][(quad * 4 + t) * 34 + 16 * j + fm] = (_Float16)sacc[j][t];

    // rescale O and row-sum by alpha
#pragma unroll
    for (int j = 0; j < 32; ++j) {
      o[j][0] *= alpha[0]; o[j][1] *= alpha[1];
      o[j][2] *= alpha[2]; o[j][3] *= alpha[3];
    }
    lacc[0] *= alpha[0]; lacc[1] *= alpha[1]; lacc[2] *= alpha[2]; lacc[3] *= alpha[3];

    half8 pf = *(const half8*)&Pls[wave][fm * 34 + quad * 8];
    lacc = __builtin_amdgcn_mfma_f32_16x16x32_f16(pf, ones, lacc, 0, 0, 0);

    // PV: O[16x512] += P[16x32] . v[32x512]
#pragma unroll
    for (int j = 0; j < 32; ++j) {
      const int chp = (((fm & 1) << 2) | quad) ^ ((fm >> 1) & 7);
      half8 vf = *(const half8*)&vbuf[((16 * j + fm) >> 1) * 64 + chp * 8];
      o[j] = __builtin_amdgcn_mfma_f32_16x16x32_f16(pf, vf, o[j], 0, 0, 0);
    }

    __syncthreads();  // all waves done with kbuf/vbuf
    if (kt < 63) stage((kt + 1) * 32);
  }

  float inv[4];
#pragma unroll
  for (int t = 0; t < 4; ++t) inv[t] = 1.f / lacc[t];
  _Float16* ob = at + ((long long)b * 2048 + q0 + 16 * wave) * 512;
#pragma unroll
  for (int j = 0; j < 32; ++j)
#pragma unroll
    for (int t = 0; t < 4; ++t)
      ob[(quad * 4 + t) * 512 + 16 * j + fm] = (_Float16)(o[j][t] * inv[t]);
}

extern "C" void kernel_launch(void* const* d_in, const int* in_sizes, int n_in,
                              void* d_out, int out_size, void* d_ws, size_t ws_size,
                              hipStream_t stream) {
  const float* x = (const float*)d_in[0];
  const float* gsc = (const float*)d_in[1];
  const float* gbi = (const float*)d_in[2];
  const float* wq = (const float*)d_in[3];
  const float* bq = (const float*)d_in[4];
  const float* wk = (const float*)d_in[5];
  const float* bk = (const float*)d_in[6];
  const float* wv = (const float*)d_in[7];
  const float* bv = (const float*)d_in[8];
  const float* wo = (const float*)d_in[9];
  const float* bo = (const float*)d_in[10];
  float* out = (float*)d_out;

  char* ws = (char*)d_ws;
  float* stats = (float*)ws;                 // 512 f32
  float* bqk = (float*)(ws + 2048);          // 1024 f32
  _Float16* wbf = (_Float16*)(ws + 8192);    // 4 * 512*512 f16
  _Float16* ht = wbf + 4 * 262144;           // [b,l,c] f16, 16 MB
  const long long EB = 8LL * 2048 * 512;
  _Float16* qkb = ht + EB;      // [b,l,1024] f16 (q||k), 32 MB
  _Float16* vm = qkb + 2 * EB;  // [b,c,l] f16, 16 MB
  _Float16* at = ht;            // attention output aliases ht (dead after V-proj)

  gn_stats<<<256, 256, 0, stream>>>(x, stats);
  gn_apply<<<dim3(32, 8, 8), 256, 0, stream>>>(x, stats, gsc, gbi, ht);
  cast_w<<<4100, 256, 0, stream>>>(wq, wk, wv, wo, bq, bk, wbf, bqk);

  // QK fused: [l, 0:1024] = ht[l,c] . (wq||wk)[o,c]^T + bqk[o]
  gemm_bt<1, 1, false><<<dim3(8, 16, 8), 256, 0, stream>>>(
      ht, 1048576LL, 512, wbf, 0LL, 512, qkb, 2097152LL, 1024, bqk, nullptr, 0LL, 1.f, 512);
  // V: [o,l] = Wv[o,c] . ht[l,c]^T + bv[o]
  gemm_bt<2, 1, false><<<dim3(8, 4, 16), 256, 0, stream>>>(
      wbf + 2 * 262144, 0LL, 512, ht, 1048576LL, 512, vm, 1048576LL, 2048, bv, nullptr, 0LL, 1.f, 512);
  // fused S -> softmax -> PV
  flash_attn<<<dim3(8, 64), 128, 0, stream>>>(qkb, vm, at);
  // Out: [o,l] = Wo[o,c] . a[l,c]^T + bo[o] + x[b,o,l]
  gemm_bt<2, 0, true><<<dim3(8, 4, 16), 256, 0, stream>>>(
      wbf + 3 * 262144, 0LL, 512, at, 1048576LL, 512, out, 1048576LL, 2048, bo, x, 1048576LL, 1.f, 512);
}

// Round 5
// 380.470 us; speedup vs baseline: 1.1326x; 1.1326x over previous
//
#include <hip/hip_runtime.h>

typedef __attribute__((ext_vector_type(8))) _Float16 half8;
typedef __attribute__((ext_vector_type(4))) float floatx4;

#define AS1 __attribute__((address_space(1)))
#define AS3 __attribute__((address_space(3)))

__device__ __forceinline__ void async_load16(const void* g, void* l) {
  __builtin_amdgcn_global_load_lds((AS1 void*)(unsigned long long)g,
                                   (AS3 void*)(unsigned long long)l, 16, 0, 0);
}

// ---------------- GroupNorm stats: one block per (b, g); region is contiguous 16*2048 floats
__global__ __launch_bounds__(256) void gn_stats(const float* __restrict__ x,
                                                float* __restrict__ stats) {
  const int bg = blockIdx.x;
  const float4* p4 = (const float4*)(x + (long long)bg * 32768);
  const int t = threadIdx.x;
  float s = 0.f, ss = 0.f;
  for (int i = t; i < 8192; i += 256) {
    float4 v = p4[i];
    s += v.x + v.y + v.z + v.w;
    ss += v.x * v.x + v.y * v.y + v.z * v.z + v.w * v.w;
  }
#pragma unroll
  for (int off = 32; off; off >>= 1) { s += __shfl_down(s, off); ss += __shfl_down(ss, off); }
  __shared__ float rs[4], rss[4];
  if ((t & 63) == 0) { rs[t >> 6] = s; rss[t >> 6] = ss; }
  __syncthreads();
  if (t == 0) {
    s = rs[0] + rs[1] + rs[2] + rs[3];
    ss = rss[0] + rss[1] + rss[2] + rss[3];
    float mean = s * (1.f / 32768.f);
    float var = ss * (1.f / 32768.f) - mean * mean;
    stats[bg] = mean;
    stats[256 + bg] = rsqrtf(var + 1e-5f);
  }
}

// ---------------- normalize + transpose: x[b,c,l] fp32 -> ht[b,l,c] fp16
__global__ __launch_bounds__(256) void gn_apply(const float* __restrict__ x,
                                                const float* __restrict__ stats,
                                                const float* __restrict__ gsc,
                                                const float* __restrict__ gbi,
                                                _Float16* __restrict__ ht) {
  __shared__ float tile[64][65];
  const int b = blockIdx.z, c0 = blockIdx.y * 64, l0 = blockIdx.x * 64;
  const int t = threadIdx.x, tr = t >> 6, tc = t & 63;
  const float* xb = x + ((long long)b * 512 + c0) * 2048 + l0;
#pragma unroll
  for (int p = 0; p < 16; ++p) {
    int row = tr + p * 4;
    tile[row][tc] = xb[(long long)row * 2048 + tc];
  }
  __syncthreads();
  const int c = c0 + tc;
  const int bg = b * 32 + (c >> 4);
  const float mean = stats[bg], rstd = stats[256 + bg];
  const float sc = gsc[c] * rstd;
  const float off = gbi[c] - mean * sc;
  _Float16* hb = ht + ((long long)b * 2048 + l0) * 512 + c0;
#pragma unroll
  for (int p = 0; p < 16; ++p) {
    int l = tr + p * 4;
    hb[(long long)l * 512 + tc] = (_Float16)(tile[tc][l] * sc + off);
  }
}

// ---------------- cast 4 weight matrices fp32 -> fp16, plus pack bq||bk into bqk (f32)
__global__ __launch_bounds__(256) void cast_w(const float* __restrict__ w0, const float* __restrict__ w1,
                                              const float* __restrict__ w2, const float* __restrict__ w3,
                                              const float* __restrict__ bq, const float* __restrict__ bk,
                                              _Float16* __restrict__ outw, float* __restrict__ bqk) {
  const long long i = (long long)blockIdx.x * 256 + threadIdx.x;
  if (blockIdx.x < 4096) {
    const int m = (int)(i >> 18);
    const int r = (int)(i & 262143);
    const float* w = (m == 0) ? w0 : (m == 1) ? w1 : (m == 2) ? w2 : w3;
    outw[i] = (_Float16)w[r];
  } else {
    const int j = (int)(i - 4096LL * 256);  // 0..1023
    bqk[j] = (j < 512) ? bq[j] : bk[j - 512];
  }
}

// ---------------- generic C[M,N] = alpha * A[M,K] * Bt[N,K]^T (+bias)(+residual)
// 128x128 tile, BK=64, XOR-swizzled LDS (conflict-free ds_read_b128),
// 4 waves x (4x4) mfma_f32_16x16x32_f16, global_load_lds width-16 staging.
template <int BIAS_MODE /*0 none,1 over n,2 over m*/, int OUT_TYPE /*0 f32,1 f16*/, bool RESIDUAL>
__global__ __launch_bounds__(256) void gemm_bt(
    const _Float16* __restrict__ A, long long sA, int lda,
    const _Float16* __restrict__ Bt, long long sB, int ldb,
    void* __restrict__ Cv, long long sC, int ldc,
    const float* __restrict__ bias,
    const float* __restrict__ resid, long long sR,
    float alpha, int K) {
  __shared__ __align__(16) _Float16 lsa[128 * 64];
  __shared__ __align__(16) _Float16 lsb[128 * 64];
  const int tid = threadIdx.x;
  const int wave = tid >> 6, lane = tid & 63;
  const int bz = blockIdx.x;  // batch -> XCD (linear_id % 8 == batch)
  const int m0 = blockIdx.y * 128, n0 = blockIdx.z * 128;
  A += (long long)bz * sA;
  Bt += (long long)bz * sB;

  const bool isA = (wave < 2);
  const _Float16* gsrc = isA ? A : Bt;
  const int ld = isA ? lda : ldb;
  const int rbase = (wave & 1) * 64;
  const int t0 = isA ? m0 : n0;
  _Float16* lbase = (isA ? lsa : lsb) + rbase * 64;
  const int grow = t0 + rbase + (lane >> 3);
  const int gcol = ((lane & 7) ^ ((lane >> 3) & 7)) * 8;

  floatx4 acc[4][4] = {};
  const int mw = (wave >> 1) * 64, nw = (wave & 1) * 64;
  const int fm = lane & 15;
  const int quad = lane >> 4;

  for (int k0 = 0; k0 < K; k0 += 64) {
    __syncthreads();
    const _Float16* g = gsrc + (long long)grow * ld + k0 + gcol;
#pragma unroll
    for (int s = 0; s < 8; ++s)
      async_load16(g + (long long)s * 8 * ld, lbase + s * 512);
    __syncthreads();
#pragma unroll
    for (int kk = 0; kk < 2; ++kk) {
      const int ca = quad + 4 * kk;
      const int cs = (ca ^ (fm & 7)) * 8;
      half8 af[4], bfr[4];
#pragma unroll
      for (int i = 0; i < 4; ++i) af[i] = *(const half8*)&lsa[(mw + 16 * i + fm) * 64 + cs];
#pragma unroll
      for (int j = 0; j < 4; ++j) bfr[j] = *(const half8*)&lsb[(nw + 16 * j + fm) * 64 + cs];
#pragma unroll
      for (int i = 0; i < 4; ++i)
#pragma unroll
        for (int j = 0; j < 4; ++j)
          acc[i][j] = __builtin_amdgcn_mfma_f32_16x16x32_f16(af[i], bfr[j], acc[i][j], 0, 0, 0);
    }
  }

  const int r0 = m0 + mw + quad * 4;
  const int c0 = n0 + nw + fm;
#pragma unroll
  for (int i = 0; i < 4; ++i) {
#pragma unroll
    for (int j = 0; j < 4; ++j) {
      const int cc = c0 + 16 * j;
#pragma unroll
      for (int t = 0; t < 4; ++t) {
        const int rr = r0 + 16 * i + t;
        float v = acc[i][j][t] * alpha;
        if (BIAS_MODE == 1) v += bias[cc];
        if (BIAS_MODE == 2) v += bias[rr];
        if (RESIDUAL) v += resid[(long long)bz * sR + (long long)rr * ldc + cc];
        const long long off = (long long)bz * sC + (long long)rr * ldc + cc;
        if (OUT_TYPE == 0) ((float*)Cv)[off] = v;
        else ((_Float16*)Cv)[off] = (_Float16)v;
      }
    }
  }
}

// ---------------- flash attention v4 = v1 structure + diagnosed fixes.
// Block = 4 waves (64 q-rows), grid (8, 32) = 256 blocks = 1/CU.
// Double-buffered l-tile 32: stage(next) issued at iteration TOP, drained by
// the single end-of-iteration barrier -> loads fly under ~2500 cyc of compute.
// vbuf: 128-B super-rows + xor swizzle (2-way max = free). Row-sum via
// ones-MFMA (no sum shuffles). O-rescale skipped when all alpha==1.
__global__ __launch_bounds__(256, 1) void flash_attn(
    const _Float16* __restrict__ qk,  // [b, l, 1024] (q | k)
    const _Float16* __restrict__ vm,  // [b, c, l]  (V^T)
    _Float16* __restrict__ at) {      // [b, l, c]
  __shared__ __align__(16) _Float16 kbuf[2][32 * 512];  // 32 KB x2: [l][c], chunk^row
  __shared__ __align__(16) _Float16 vbuf[2][256 * 64];  // 32 KB x2: super-row = 2 c-rows
  __shared__ __align__(16) _Float16 Pls[4][16 * 34];    // per-wave P transpose
  const int tid = threadIdx.x, wave = tid >> 6, lane = tid & 63;
  const int fm = lane & 15, quad = lane >> 4;
  const int b = blockIdx.x, q0 = blockIdx.y * 64;
  const _Float16* qb = qk + (long long)b * 2097152;
  const _Float16* kb = qb + 512;
  const _Float16* vb = vm + (long long)b * 1048576;

  // q A-frags: rows q0+16*wave+fm, k-chunk ks*32+quad*8, pre-scaled by 512^-0.5
  half8 qf[16];
  {
    const _Float16* qrow = qb + (long long)(q0 + 16 * wave + fm) * 1024 + quad * 8;
#pragma unroll
    for (int ks = 0; ks < 16; ++ks) {
      half8 h = *(const half8*)(qrow + ks * 32);
#pragma unroll
      for (int e = 0; e < 8; ++e) h[e] = (_Float16)((float)h[e] * 0.044194173824159216f);
      qf[ks] = h;
    }
  }
  half8 ones;
#pragma unroll
  for (int e = 0; e < 8; ++e) ones[e] = (_Float16)1.0f;

  floatx4 o[32] = {};  // O rows 16w+quad*4+t, cols fm+16j
  floatx4 lacc = {};   // row sums, same C-layout rows
  float m_i[4];
#pragma unroll
  for (int t = 0; t < 4; ++t) m_i[t] = -1e30f;

  auto stage = [&](int l0, int buf) {
    // k-tile [32 l x 512 c]: 16B chunk ch of row stored at ch^(row&7)
#pragma unroll
    for (int s = 0; s < 8; ++s) {
      int i = s * 256 + tid;
      int row = i >> 6, ch = i & 63;
      async_load16(kb + (long long)(l0 + row) * 1024 + ((ch ^ (row & 7)) << 3),
                   &kbuf[buf][i * 8]);
    }
    // v-tile: super-row r = c-rows {2r, 2r+1} over 32 l; chunk pos swizzled ^(r&7)
#pragma unroll
    for (int s = 0; s < 8; ++s) {
      int i = s * 256 + tid;
      int r = i >> 3, ch = (i & 7) ^ (r & 7);
      async_load16(vb + (long long)(2 * r + (ch >> 2)) * 2048 + l0 + ((ch & 3) << 3),
                   &vbuf[buf][i * 8]);
    }
  };

  stage(0, 0);
  __syncthreads();

  for (int kt = 0; kt < 64; ++kt) {
    const int cur = kt & 1;
    if (kt < 63) stage((kt + 1) * 32, cur ^ 1);  // drains at end-of-iter barrier

    // S-tile: rows 16w+quad*4+t, cols kt*32+fm+16j; 4 independent MFMA chains
    floatx4 sA[2] = {}, sB[2] = {};
#pragma unroll
    for (int ks = 0; ks < 16; ks += 2) {
#pragma unroll
      for (int j = 0; j < 2; ++j) {
        const int ch0 = (ks * 4 + quad) ^ (fm & 7);
        half8 b0 = *(const half8*)&kbuf[cur][(16 * j + fm) * 512 + ch0 * 8];
        sA[j] = __builtin_amdgcn_mfma_f32_16x16x32_f16(qf[ks], b0, sA[j], 0, 0, 0);
        const int ch1 = ((ks + 1) * 4 + quad) ^ (fm & 7);
        half8 b1 = *(const half8*)&kbuf[cur][(16 * j + fm) * 512 + ch1 * 8];
        sB[j] = __builtin_amdgcn_mfma_f32_16x16x32_f16(qf[ks + 1], b1, sB[j], 0, 0, 0);
      }
    }
    floatx4 sacc[2];
    sacc[0] = sA[0] + sB[0];
    sacc[1] = sA[1] + sB[1];

    // online softmax (rows in quad; 32 cols across 16 lanes x 2 regs)
    float alpha[4];
#pragma unroll
    for (int t = 0; t < 4; ++t) {
      float mx = fmaxf(sacc[0][t], sacc[1][t]);
#pragma unroll
      for (int d = 1; d < 16; d <<= 1) mx = fmaxf(mx, __shfl_xor(mx, d));
      float mn = fmaxf(m_i[t], mx);
      alpha[t] = __expf(m_i[t] - mn);
      m_i[t] = mn;
      sacc[0][t] = __expf(sacc[0][t] - mn);
      sacc[1][t] = __expf(sacc[1][t] - mn);
    }

    // P: C-layout -> wave-private LDS -> A-layout (lgkm ordering, no barrier)
#pragma unroll
    for (int j = 0; j < 2; ++j)
#pragma unroll
      for (int t = 0; t < 4; ++t)
        Pls[wave][(quad * 4 + t) * 34 + 16 * j + fm] = (_Float16)sacc[j][t];

    // O/l rescale, skipped when max unchanged (alpha==1 exactly via exp(0))
    if (__any((alpha[0] < 1.f) | (alpha[1] < 1.f) | (alpha[2] < 1.f) | (alpha[3] < 1.f))) {
#pragma unroll
      for (int j = 0; j < 32; ++j) {
        o[j][0] *= alpha[0]; o[j][1] *= alpha[1];
        o[j][2] *= alpha[2]; o[j][3] *= alpha[3];
      }
      lacc[0] *= alpha[0]; lacc[1] *= alpha[1];
      lacc[2] *= alpha[2]; lacc[3] *= alpha[3];
    }

    half8 pf = *(const half8*)&Pls[wave][fm * 34 + quad * 8];
    lacc = __builtin_amdgcn_mfma_f32_16x16x32_f16(pf, ones, lacc, 0, 0, 0);

    // PV: O[16x512] += P[16x32] . v[32x512]
    const int chp8 = ((((fm & 1) << 2) | quad) ^ ((fm >> 1) & 7)) * 8;
    const int rlo = fm >> 1;
#pragma unroll
    for (int j = 0; j < 32; ++j) {
      half8 vf = *(const half8*)&vbuf[cur][(8 * j + rlo) * 64 + chp8];
      o[j] = __builtin_amdgcn_mfma_f32_16x16x32_f16(pf, vf, o[j], 0, 0, 0);
    }

    __syncthreads();  // drains next-tile staging; all waves done with cur bufs
  }

  float inv[4];
#pragma unroll
  for (int t = 0; t < 4; ++t) inv[t] = 1.f / lacc[t];
  _Float16* ob = at + ((long long)b * 2048 + q0 + 16 * wave) * 512;
#pragma unroll
  for (int j = 0; j < 32; ++j)
#pragma unroll
    for (int t = 0; t < 4; ++t)
      ob[(quad * 4 + t) * 512 + 16 * j + fm] = (_Float16)(o[j][t] * inv[t]);
}

extern "C" void kernel_launch(void* const* d_in, const int* in_sizes, int n_in,
                              void* d_out, int out_size, void* d_ws, size_t ws_size,
                              hipStream_t stream) {
  const float* x = (const float*)d_in[0];
  const float* gsc = (const float*)d_in[1];
  const float* gbi = (const float*)d_in[2];
  const float* wq = (const float*)d_in[3];
  const float* bq = (const float*)d_in[4];
  const float* wk = (const float*)d_in[5];
  const float* bk = (const float*)d_in[6];
  const float* wv = (const float*)d_in[7];
  const float* bv = (const float*)d_in[8];
  const float* wo = (const float*)d_in[9];
  const float* bo = (const float*)d_in[10];
  float* out = (float*)d_out;

  char* ws = (char*)d_ws;
  float* stats = (float*)ws;                 // 512 f32
  float* bqk = (float*)(ws + 2048);          // 1024 f32
  _Float16* wbf = (_Float16*)(ws + 8192);    // 4 * 512*512 f16
  _Float16* ht = wbf + 4 * 262144;           // [b,l,c] f16, 16 MB
  const long long EB = 8LL * 2048 * 512;
  _Float16* qkb = ht + EB;      // [b,l,1024] f16 (q||k), 32 MB
  _Float16* vm = qkb + 2 * EB;  // [b,c,l] f16, 16 MB
  _Float16* at = ht;            // attention output aliases ht (dead after V-proj)

  gn_stats<<<256, 256, 0, stream>>>(x, stats);
  gn_apply<<<dim3(32, 8, 8), 256, 0, stream>>>(x, stats, gsc, gbi, ht);
  cast_w<<<4100, 256, 0, stream>>>(wq, wk, wv, wo, bq, bk, wbf, bqk);

  // QK fused: [l, 0:1024] = ht[l,c] . (wq||wk)[o,c]^T + bqk[o]
  gemm_bt<1, 1, false><<<dim3(8, 16, 8), 256, 0, stream>>>(
      ht, 1048576LL, 512, wbf, 0LL, 512, qkb, 2097152LL, 1024, bqk, nullptr, 0LL, 1.f, 512);
  // V: [o,l] = Wv[o,c] . ht[l,c]^T + bv[o]
  gemm_bt<2, 1, false><<<dim3(8, 4, 16), 256, 0, stream>>>(
      wbf + 2 * 262144, 0LL, 512, ht, 1048576LL, 512, vm, 1048576LL, 2048, bv, nullptr, 0LL, 1.f, 512);
  // fused S -> softmax -> PV
  flash_attn<<<dim3(8, 32), 256, 0, stream>>>(qkb, vm, at);
  // Out: [o,l] = Wo[o,c] . a[l,c]^T + bo[o] + x[b,o,l]
  gemm_bt<2, 0, true><<<dim3(8, 4, 16), 256, 0, stream>>>(
      wbf + 3 * 262144, 0LL, 512, at, 1048576LL, 512, out, 1048576LL, 2048, bo, x, 1048576LL, 1.f, 512);
}